// Round 9
// baseline (261.868 us; speedup 1.0000x reference)
//
#include <hip/hip_runtime.h>

#define NCOMP 8
#define NCONT 56
#define NCAT 8
#define NU 100
#define NROWS 32768
#define SEPC 1e-3f
#define T1F 10.0f

// native type of __builtin_amdgcn_cvt_pkrtz / __builtin_amdgcn_fdot2 operands
typedef __fp16 f16x2 __attribute__((ext_vector_type(2)));
// arithmetic-friendly fp16 pair for the packed butterfly add
typedef _Float16 h2arith __attribute__((ext_vector_type(2)));

// One combined weight array: per feature f (0..55), 35 float4 "roles":
//  role 2c+t      : Wh comp c, k=8t..8t+7   (16 roles)
//  role 16+2c+t   : Wv comp c, k=8t..8t+7   (16 roles)
//  role 32+t      : Wic,       k=8t..8t+7   (2 roles)
//  role 34        : pad
#define FSTRIDE 35

union H8 { f16x2 h2[4]; float4 f4; };

__device__ __forceinline__ float sp(float x) {
    // softplus = ln2 * log2(1 + 2^(x*log2e)) via v_exp_f32/v_log_f32
    return 0.69314718f * __builtin_amdgcn_logf(1.0f + __builtin_amdgcn_exp2f(x * 1.44269504f));
}

__device__ __forceinline__ f16x2 pkrtz(float a, float b) {
    return __builtin_amdgcn_cvt_pkrtz(a, b);
}

__device__ __forceinline__ float fdot2(f16x2 a, f16x2 b, float c) {
    return __builtin_amdgcn_fdot2(a, b, c, false);
}

__device__ __forceinline__ h2arith h2shfl_xor(h2arith v, int off) {
    int i = __builtin_bit_cast(int, v);
    i = __shfl_xor(i, off, 64);
    return __builtin_bit_cast(h2arith, i);
}

// ---------------- kernel 1: pure-stream one-hot decode ----------------
// Bcat (32768 x 800 fp32 one-hot) -> codes (32768 x 8 int). Each float4
// never straddles a 100-wide category block (100 % 4 == 0). Exactly one
// element per (row, cat-block) is 1.0, so every codes slot gets written.
__global__ __launch_bounds__(256) void decode_kernel(
    const float* __restrict__ Bcat, int* __restrict__ codes)
{
    const int total = NROWS * 200;           // float4 count
    int idx = blockIdx.x * 256 + threadIdx.x;
    const int step = gridDim.x * 256;
    for (; idx < total; idx += step) {
        float4 q = ((const float4*)Bcat)[idx];
        int row = idx / 200;
        int pos = idx - row * 200;
        float n = (float)(4 * pos);
        // dot with (n+1..n+4): exact for one-hot {0,1} entries
        float sc = q.x * (n + 1.0f) + q.y * (n + 2.0f) + q.z * (n + 3.0f) + q.w * (n + 4.0f);
        if (sc > 0.5f) {
            int p = (int)sc - 1;             // element index within row's 800
            int f = p / NU;
            codes[row * NCAT + f] = p - f * NU;
        }
    }
}

// One continuous-feature accumulation against LDS weights.
__device__ __forceinline__ void acc_cont(const float4* __restrict__ pw,
                                         float4 a0, float4 a1, float4 a2, float4 a3,
                                         float* sh, float* sw, float& ic) {
    f16x2 ba[8];
    ba[0] = pkrtz(a0.x, a0.y); ba[1] = pkrtz(a0.z, a0.w);
    ba[2] = pkrtz(a1.x, a1.y); ba[3] = pkrtz(a1.z, a1.w);
    ba[4] = pkrtz(a2.x, a2.y); ba[5] = pkrtz(a2.z, a2.w);
    ba[6] = pkrtz(a3.x, a3.y); ba[7] = pkrtz(a3.z, a3.w);
#pragma unroll
    for (int c = 0; c < NCOMP; ++c) {
        H8 u0, u1, v0, v1;
        u0.f4 = pw[2 * c];      u1.f4 = pw[2 * c + 1];
        v0.f4 = pw[16 + 2 * c]; v1.f4 = pw[17 + 2 * c];
        float hA = 0.0f, vA = 0.0f;
#pragma unroll
        for (int p = 0; p < 4; ++p) {
            hA = fdot2(ba[p], u0.h2[p], hA);
            vA = fdot2(ba[p], v0.h2[p], vA);
        }
#pragma unroll
        for (int p = 0; p < 4; ++p) {
            hA = fdot2(ba[4 + p], u1.h2[p], hA);
            vA = fdot2(ba[4 + p], v1.h2[p], vA);
        }
        sh[c] += sp(hA);
        sw[c] += sp(vA);
    }
    H8 i0, i1;
    i0.f4 = pw[32]; i1.f4 = pw[33];
    float iA = 0.0f;
#pragma unroll
    for (int p = 0; p < 4; ++p) iA = fdot2(ba[p], i0.h2[p], iA);
#pragma unroll
    for (int p = 0; p < 4; ++p) iA = fdot2(ba[4 + p], i1.h2[p], iA);
    ic += iA;   // IC has no softplus
}

// ---------------- kernel 2: GAM compute (no Bcat scan) ----------------
// cap 128 VGPR; do NOT force 8 waves/EU (round 6: (512,8) => scratch spill).
__global__ __launch_bounds__(512, 4) void tpm_kernel(
    const float* __restrict__ B, const int* __restrict__ codes,
    const float* __restrict__ Wh, const float* __restrict__ Whc, const float* __restrict__ bh,
    const float* __restrict__ Wv, const float* __restrict__ Wvc, const float* __restrict__ bv,
    const float* __restrict__ Wic, const float* __restrict__ Wicc, const float* __restrict__ bic,
    float* __restrict__ out)
{
    __shared__ float4 sW[NCONT * FSTRIDE];  // 31360 B, f16 weights (H|V|IC)
    __shared__ float2 sBias[NCOMP];         // (sp(bh), sp(bv))
    __shared__ float  sBic;

    const int tid = threadIdx.x;

    // ---- stage Wh/Wv as f16: idx in [0,896) handles (icp = i*8+c, t) ----
    for (int idx = tid; idx < 896; idx += 512) {
        int icp = idx % 448, t = idx / 448;
        int i = icp >> 3, c = icp & 7;
        const float* gh = Wh + (size_t)(8 * t) * 448 + icp;
        const float* gv = Wv + (size_t)(8 * t) * 448 + icp;
        H8 uh, uv;
#pragma unroll
        for (int p = 0; p < 4; ++p) {
            uh.h2[p] = pkrtz(gh[(2 * p) * 448], gh[(2 * p + 1) * 448]);
            uv.h2[p] = pkrtz(gv[(2 * p) * 448], gv[(2 * p + 1) * 448]);
        }
        sW[i * FSTRIDE + 2 * c + t] = uh.f4;
        sW[i * FSTRIDE + 16 + 2 * c + t] = uv.f4;
    }
    if (tid < 112) {
        int i = tid % 56, t = tid / 56;
        const float* gi = Wic + (size_t)(8 * t) * 56 + i;
        H8 u;
#pragma unroll
        for (int p = 0; p < 4; ++p)
            u.h2[p] = pkrtz(gi[(2 * p) * 56], gi[(2 * p + 1) * 56]);
        sW[i * FSTRIDE + 32 + t] = u.f4;
    }
    if (tid < NCOMP) sBias[tid] = make_float2(sp(bh[tid]), sp(bv[tid]));
    if (tid == NCOMP) sBic = bic[0];
    __syncthreads();

    const int lane = tid & 63;
    const int widx = tid >> 6;      // 0..7
    const int s = lane & 15;        // sublane: feature group
    const int g = lane >> 4;        // row group 0..3
    const int R0 = (((blockIdx.x << 3) + widx) << 2);  // 4 rows per wave, exact cover
    const int r = R0 + g;           // this group's row
    const float* browp = B + (size_t)r * 896;

    // ---- prefetch the categorical gather (used only in pass 3) ----
    float4 p3a, p3b, p3c, p3d;
    float p3ic = 0.0f;
    if (s >= 8) {
        int fi = s - 8;
        int cc = codes[r * NCAT + fi];
        int gA = fi * NU + cc;
        const float4* qh = (const float4*)(Whc + gA * 8);
        const float4* qv = (const float4*)(Wvc + gA * 8);
        p3a = qh[0]; p3b = qh[1]; p3c = qv[0]; p3d = qv[1];
        p3ic = Wicc[gA];
    }

    // ---- accumulators: 17 channels x 1 row ----
    float sh[NCOMP], sw[NCOMP];
    float ic = 0.0f;
#pragma unroll
    for (int c = 0; c < NCOMP; ++c) { sh[c] = sw[c] = 0.0f; }

    // ---- prefetch pass-0 B data ----
    float4 cb0, cb1, cb2, cb3;
    {
        const float4* p = (const float4*)(browp + s * 16);
        cb0 = p[0]; cb1 = p[1]; cb2 = p[2]; cb3 = p[3];
    }

    // ---- passes 0..2 (all lanes continuous), pipelined ----
#pragma unroll
    for (int j = 0; j < 3; ++j) {
        float4 nb0, nb1, nb2, nb3;
        if (j < 2) {
            const float4* p = (const float4*)(browp + (s + 16 * (j + 1)) * 16);
            nb0 = p[0]; nb1 = p[1]; nb2 = p[2]; nb3 = p[3];
        } else {
            // pass-3 B data; clamp f for cat lanes (s>=8) to stay in-bounds,
            // their copy is discarded.
            int f3 = (s < 8) ? (s + 48) : 48;
            const float4* p = (const float4*)(browp + f3 * 16);
            nb0 = p[0]; nb1 = p[1]; nb2 = p[2]; nb3 = p[3];
        }
        acc_cont(sW + (s + 16 * j) * FSTRIDE, cb0, cb1, cb2, cb3, sh, sw, ic);
        cb0 = nb0; cb1 = nb1; cb2 = nb2; cb3 = nb3;
    }

    // ---- pass 3: cont for s<8 (buffered), cat for s>=8 (prefetched) ----
    if (s < 8) {
        acc_cont(sW + (s + 48) * FSTRIDE, cb0, cb1, cb2, cb3, sh, sw, ic);
    } else {
        sh[0] += sp(p3a.x); sh[1] += sp(p3a.y); sh[2] += sp(p3a.z); sh[3] += sp(p3a.w);
        sh[4] += sp(p3b.x); sh[5] += sp(p3b.y); sh[6] += sp(p3b.z); sh[7] += sp(p3b.w);
        sw[0] += sp(p3c.x); sw[1] += sp(p3c.y); sw[2] += sp(p3c.z); sw[3] += sp(p3c.w);
        sw[4] += sp(p3d.x); sw[5] += sp(p3d.y); sw[6] += sp(p3d.z); sw[7] += sp(p3d.w);
        ic += p3ic;
    }

    // ---- pack and 4-step butterfly within each 16-lane group ----
    h2arith hw[NCOMP];
#pragma unroll
    for (int c = 0; c < NCOMP; ++c)
        hw[c] = __builtin_bit_cast(h2arith, pkrtz(sh[c], sw[c]));
#pragma unroll
    for (int off = 8; off >= 1; off >>= 1) {
#pragma unroll
        for (int c = 0; c < NCOMP; ++c)
            hw[c] = hw[c] + h2shfl_xor(hw[c], off);
        ic += __shfl_xor(ic, off, 64);
    }

    // ---- sublanes 0..8 emit (t, x) for this group's row ----
    if (s < 9) {
        int m = (s == 8) ? 7 : s;
        float tj = SEPC * (float)s;
        float xj = ic + sBic;
#pragma unroll
        for (int c = 0; c < NCOMP; ++c) {
            float2 bb2 = sBias[c];
            if (c < m) tj += (float)hw[c][0] + bb2.x;
            if (c < s) {
                float vv = (float)hw[c][1] + bb2.y;
                xj += (c & 1) ? -vv : vv;
            }
        }
        if (s == 8) tj = fmaxf(tj, T1F);
        float2 o; o.x = tj; o.y = xj;
        ((float2*)out)[(size_t)r * 9 + s] = o;
    }
}

extern "C" void kernel_launch(void* const* d_in, const int* in_sizes, int n_in,
                              void* d_out, int out_size, void* d_ws, size_t ws_size,
                              hipStream_t stream) {
    (void)in_sizes; (void)n_in; (void)out_size; (void)ws_size;
    const float* B    = (const float*)d_in[0];
    const float* Bcat = (const float*)d_in[1];
    const float* Wh   = (const float*)d_in[2];
    const float* Whc  = (const float*)d_in[3];
    const float* bh   = (const float*)d_in[4];
    const float* Wv   = (const float*)d_in[5];
    const float* Wvc  = (const float*)d_in[6];
    const float* bv   = (const float*)d_in[7];
    const float* Wic  = (const float*)d_in[8];
    const float* Wicc = (const float*)d_in[9];
    const float* bic  = (const float*)d_in[10];
    float* out = (float*)d_out;
    int* codes = (int*)d_ws;   // 32768 x 8 ints = 1 MB, fully overwritten by decode

    // kernel 1: pure stream, 2048 x 256 = 524288 threads over 6.55M float4
    hipLaunchKernelGGL(decode_kernel, dim3(2048), dim3(256), 0, stream, Bcat, codes);
    // kernel 2: 1024 blocks x 8 waves x 4 rows = 32768 rows
    hipLaunchKernelGGL(tpm_kernel, dim3(1024), dim3(512), 0, stream,
                       B, codes, Wh, Whc, bh, Wv, Wvc, bv, Wic, Wicc, bic, out);
}